// Round 10
// baseline (434.285 us; speedup 1.0000x reference)
//
#include <hip/hip_runtime.h>

using bf16_t = __bf16;
typedef __bf16 bf16x4 __attribute__((ext_vector_type(4)));
typedef __bf16 bf16x8 __attribute__((ext_vector_type(8)));
typedef float floatx4 __attribute__((ext_vector_type(4)));

#define MFMA_BF16(a, b, c) __builtin_amdgcn_mfma_f32_16x16x32_bf16((a), (b), (c), 0, 0, 0)

__device__ __forceinline__ void async_ld16(bf16_t* lds_dst, const bf16_t* g_src) {
    __builtin_amdgcn_global_load_lds(
        (const __attribute__((address_space(1))) void*)g_src,
        (__attribute__((address_space(3))) void*)lds_dst, 16, 0, 0);
}

// ---------------------------------------------------------------------------
// fp32 -> bf16 cast, 8 elements/thread
// ---------------------------------------------------------------------------
__global__ __launch_bounds__(256) void cast_bf16(const float* __restrict__ src,
                                                 bf16_t* __restrict__ dst, int n8) {
    int i = blockIdx.x * 256 + threadIdx.x;
    if (i < n8) {
        const floatx4 a = *(const floatx4*)(src + (size_t)i * 8);
        const floatx4 b = *(const floatx4*)(src + (size_t)i * 8 + 4);
        bf16x8 r;
        r[0] = (bf16_t)a[0]; r[1] = (bf16_t)a[1]; r[2] = (bf16_t)a[2]; r[3] = (bf16_t)a[3];
        r[4] = (bf16_t)b[0]; r[5] = (bf16_t)b[1]; r[6] = (bf16_t)b[2]; r[7] = (bf16_t)b[3];
        *(bf16x8*)(dst + (size_t)i * 8) = r;
    }
}

// ---------------------------------------------------------------------------
// lam = exp(sum(lq1*lk1)) - exp(sum(lq2*lk2)) + 0.2   (DEPTH=0)
// ---------------------------------------------------------------------------
__global__ void lam_kernel(const float* lq1, const float* lq2,
                           const float* lk1, const float* lk2, float* lamp) {
    int l = threadIdx.x;
    float p1 = lq1[l] * lk1[l];
    float p2 = lq2[l] * lk2[l];
    #pragma unroll
    for (int d = 1; d < 64; d <<= 1) {
        p1 += __shfl_xor(p1, d);
        p2 += __shfl_xor(p2, d);
    }
    if (l == 0) *lamp = expf(p1) - expf(p2) + 0.2f;
}

// ---------------------------------------------------------------------------
// GEMM (bf16): C[m][n] = sum_k A[m][k]*B[n][k]. BK=32, global_load_lds
// width-16 staging into [row][32] LDS, 16x16x32 MFMA, 2x2 waves.
// QKV_EPI routes into Qb/Kb ([inst][h][n][64], unrotated) and Vt ([h*128+vc][n]).
// ---------------------------------------------------------------------------
template <int BM, int BN, bool QKV_EPI, typename TC>
__global__ __launch_bounds__(256) void gemm_bt(const bf16_t* __restrict__ A,
                                               const bf16_t* __restrict__ B,
                                               TC* __restrict__ C,
                                               bf16_t* __restrict__ Qb,
                                               bf16_t* __restrict__ Kb,
                                               bf16_t* __restrict__ Vt,
                                               int M, int N, int K) {
    constexpr int BK = 32;
    __shared__ __align__(16) bf16_t As[BM * BK];
    __shared__ __align__(16) bf16_t Bs[BN * BK];
    const int t = threadIdx.x;
    const int lane = t & 63, wave = t >> 6;
    const int q4 = lane >> 4, m16 = lane & 15;
    const int mblk = blockIdx.y * BM, nblk = blockIdx.x * BN;
    const int wr = wave >> 1, wc = wave & 1;
    constexpr int WM = BM / 2, WN = BN / 2;
    constexpr int NI = WM / 16, NJ = WN / 16;
    constexpr int AR = BM * BK / 2048;
    constexpr int BR = BN * BK / 2048;

    floatx4 acc[NI][NJ] = {};

    for (int k0 = 0; k0 < K; k0 += BK) {
        __syncthreads();
        #pragma unroll
        for (int rr = 0; rr < AR; ++rr) {
            int f = rr * 256 + t;
            async_ld16(&As[f * 8], &A[(size_t)(mblk + (f >> 2)) * K + k0 + (f & 3) * 8]);
        }
        #pragma unroll
        for (int rr = 0; rr < BR; ++rr) {
            int f = rr * 256 + t;
            async_ld16(&Bs[f * 8], &B[(size_t)(nblk + (f >> 2)) * K + k0 + (f & 3) * 8]);
        }
        __syncthreads();

        bf16x8 a[NI], b[NJ];
        #pragma unroll
        for (int i = 0; i < NI; ++i)
            a[i] = *(const bf16x8*)&As[(wr * WM + i * 16 + m16) * 32 + q4 * 8];
        #pragma unroll
        for (int j = 0; j < NJ; ++j)
            b[j] = *(const bf16x8*)&Bs[(wc * WN + j * 16 + m16) * 32 + q4 * 8];
        #pragma unroll
        for (int i = 0; i < NI; ++i)
            #pragma unroll
            for (int j = 0; j < NJ; ++j)
                acc[i][j] = MFMA_BF16(a[i], b[j], acc[i][j]);
    }

    #pragma unroll
    for (int i = 0; i < NI; ++i)
        #pragma unroll
        for (int j = 0; j < NJ; ++j) {
            int n = nblk + wc * WN + j * 16 + m16;
            #pragma unroll
            for (int r = 0; r < 4; ++r) {
                int m = mblk + wr * WM + i * 16 + q4 * 4 + r;
                if constexpr (QKV_EPI) {
                    bf16_t val = (bf16_t)acc[i][j][r];
                    int comp = n >> 10, h = (n >> 6) & 15, e = n & 63;
                    if (comp < 2)
                        Qb[(size_t)((comp * 16 + h) * 2048 + m) * 64 + e] = val;
                    else if (comp < 4)
                        Kb[(size_t)(((comp - 2) * 16 + h) * 2048 + m) * 64 + e] = val;
                    else
                        Vt[(size_t)(h * 128 + (comp - 4) * 64 + e) * 2048 + m] = val;
                } else {
                    C[(size_t)m * N + n] = (TC)acc[i][j][r];
                }
            }
        }
}

// ---------------------------------------------------------------------------
// In-place rotary on Qb/Kb [inst][h][n][64]
// ---------------------------------------------------------------------------
__global__ __launch_bounds__(256) void rotary_inplace(bf16_t* __restrict__ Qb,
                                                      bf16_t* __restrict__ Kb) {
    int t = blockIdx.x * 256 + threadIdx.x;
    int e = t & 63, h = (t >> 6) & 15, n = t >> 10;
    float invf = exp2f(-(float)e * (13.287712379549449f / 64.0f));
    float ang = (float)n * invf;
    float s, c;
    sincosf(ang, &s, &c);
    int off = (h * 2048 + n) * 64 + e;
    float q1 = (float)Qb[off], q2 = (float)Qb[off + 2097152];
    Qb[off]           = (bf16_t)(q1 * c - q2 * s);
    Qb[off + 2097152] = (bf16_t)(q2 * c + q1 * s);
    float k1 = (float)Kb[off], k2 = (float)Kb[off + 2097152];
    Kb[off]           = (bf16_t)(k1 * c - k2 * s);
    Kb[off + 2097152] = (bf16_t)(k2 * c + k1 * s);
}

// ---------------------------------------------------------------------------
// Differential flash attention, v4 — LDS-read amortization.
// 2 waves/block (128 thr); each wave owns 32 q-rows (2 subtiles u of 16):
// every kf/vf LDS fragment read feeds 2 MFMAs -> per-qrow LDS cost halves
// vs v2/v3. S^T orientation (A=K, B=Q) for b64 P-stores; Pf wave-private
// (no barrier between P write/read); fixed-max softmax; ones-MFMA row sums.
// grid (32 qtiles x 16 heads), 64 keys/chunk, 2 barriers/chunk.
// ---------------------------------------------------------------------------
__global__ __launch_bounds__(128, 2) void flash_diff(const bf16_t* __restrict__ Qb,
                                                     const bf16_t* __restrict__ Kb,
                                                     const bf16_t* __restrict__ Vt,
                                                     const float* __restrict__ lamp,
                                                     bf16_t* __restrict__ Ao) {
    constexpr int N = 2048, BN = 64, PM = 17;
    __shared__ __align__(16) bf16_t Kf[2 * 4 * 2 * 4 * PM * 8];      // [i][s][half][qq][PM][8]
    __shared__ __align__(16) bf16_t Vf[8 * 2 * 4 * PM * 8];          // [tt][half][qq][PM][8]
    __shared__ __align__(16) bf16_t Pf[2 * 2 * 2 * 2 * 4 * 16 * 8];  // [w][i][u][half][quad][m16][8]
    const int t = threadIdx.x, lane = t & 63, w = t >> 6;  // w in {0,1}
    const int q4 = lane >> 4, m16 = lane & 15;
    const int h = blockIdx.y, qt = blockIdx.x;
    const float lam = *lamp;
    const float cexp = 0.125f * 1.4426950408889634f;  // scale * log2(e)

    // Q fragments, used as B operand (free dim = qrow = m16, k = q4*8+j)
    bf16x8 qf[2][2][2];  // [inst][u][half]
    #pragma unroll
    for (int i = 0; i < 2; ++i)
        #pragma unroll
        for (int u = 0; u < 2; ++u) {
            const int qrow = qt * 64 + w * 32 + u * 16 + m16;
            #pragma unroll
            for (int kc = 0; kc < 2; ++kc)
                qf[i][u][kc] = *(const bf16x8*)&Qb[(size_t)((i * 16 + h) * 2048 + qrow) * 64 + kc * 32 + q4 * 8];
        }

    bf16x8 ones;
    #pragma unroll
    for (int j = 0; j < 8; ++j) ones[j] = (bf16_t)1.0f;

    floatx4 O[2][2][8] = {};   // [inst][u][tt]
    floatx4 sm[2][2] = {};     // [inst][u]

    for (int k0 = 0; k0 < N; k0 += BN) {
        // ---- global loads to regs (overlap prev chunk's MFMA tail) ----
        bf16x8 sK[8], sV[8];
        #pragma unroll
        for (int rr = 0; rr < 8; ++rr) {
            int f = rr * 128 + t;
            int inst = f >> 9, key = (f >> 3) & 63, g = f & 7;
            sK[rr] = *(const bf16x8*)&Kb[(size_t)((inst * 16 + h) * 2048 + k0 + key) * 64 + g * 8];
        }
        #pragma unroll
        for (int rr = 0; rr < 8; ++rr) {
            int f = rr * 128 + t;
            int vc = f >> 3, g = f & 7;
            sV[rr] = *(const bf16x8*)&Vt[(size_t)(h * 128 + vc) * 2048 + k0 + g * 8];
        }
        __syncthreads();  // prev chunk's Kf/Vf reads complete
        #pragma unroll
        for (int rr = 0; rr < 8; ++rr) {
            int f = rr * 128 + t;
            int inst = f >> 9, key = (f >> 3) & 63, g = f & 7;
            int s = key >> 4, mm = key & 15, half = g >> 2, qq = g & 3;
            *(bf16x8*)&Kf[((((inst * 4 + s) * 2 + half) * 4 + qq) * PM + mm) * 8] = sK[rr];
        }
        #pragma unroll
        for (int rr = 0; rr < 8; ++rr) {
            int f = rr * 128 + t;
            int vc = f >> 3, g = f & 7;
            int tt = vc >> 4, mm = vc & 15, half = g >> 2, qq = g & 3;
            *(bf16x8*)&Vf[(((tt * 2 + half) * 4 + qq) * PM + mm) * 8] = sV[rr];
        }
        __syncthreads();  // staged tiles visible

        // ---- S^T = K Q^T per subtile, p = exp2(S*cexp), b64 P-store ----
        #pragma unroll
        for (int i = 0; i < 2; ++i) {
            #pragma unroll
            for (int s = 0; s < 4; ++s) {
                const bf16x8 kf0 = *(const bf16x8*)&Kf[((((i * 4 + s) * 2 + 0) * 4 + q4) * PM + m16) * 8];
                const bf16x8 kf1 = *(const bf16x8*)&Kf[((((i * 4 + s) * 2 + 1) * 4 + q4) * PM + m16) * 8];
                #pragma unroll
                for (int u = 0; u < 2; ++u) {
                    floatx4 sacc = {};
                    sacc = MFMA_BF16(kf0, qf[i][u][0], sacc);  // D[key][qrow]
                    sacc = MFMA_BF16(kf1, qf[i][u][1], sacc);
                    bf16x4 pv;
                    #pragma unroll
                    for (int r = 0; r < 4; ++r) pv[r] = (bf16_t)exp2f(sacc[r] * cexp);
                    // key = 16s+4q4+r -> A-order: half=s>>1, quad=2(s&1)+(q4>>1), j=4(q4&1)+r
                    const int half = s >> 1, quad = 2 * (s & 1) + (q4 >> 1), j4 = 4 * (q4 & 1);
                    *(bf16x4*)&Pf[((((((w * 2 + i) * 2 + u) * 2 + half) * 4 + quad) * 16 + m16) * 8) + j4] = pv;
                }
            }
        }
        // Pf wave-private: within-wave lgkmcnt ordering suffices, no barrier.

        // ---- P reads (A-frag), row sums, PV ----
        bf16x8 pf[2][2][2];
        #pragma unroll
        for (int i = 0; i < 2; ++i)
            #pragma unroll
            for (int u = 0; u < 2; ++u) {
                pf[i][u][0] = *(const bf16x8*)&Pf[(((((w * 2 + i) * 2 + u) * 2 + 0) * 4 + q4) * 16 + m16) * 8];
                pf[i][u][1] = *(const bf16x8*)&Pf[(((((w * 2 + i) * 2 + u) * 2 + 1) * 4 + q4) * 16 + m16) * 8];
                sm[i][u] = MFMA_BF16(pf[i][u][0], ones, sm[i][u]);
                sm[i][u] = MFMA_BF16(pf[i][u][1], ones, sm[i][u]);
            }
        #pragma unroll
        for (int tt = 0; tt < 8; ++tt) {
            const bf16x8 vf0 = *(const bf16x8*)&Vf[(((tt * 2 + 0) * 4 + q4) * PM + m16) * 8];
            const bf16x8 vf1 = *(const bf16x8*)&Vf[(((tt * 2 + 1) * 4 + q4) * PM + m16) * 8];
            #pragma unroll
            for (int i = 0; i < 2; ++i)
                #pragma unroll
                for (int u = 0; u < 2; ++u) {
                    O[i][u][tt] = MFMA_BF16(pf[i][u][0], vf0, O[i][u][tt]);
                    O[i][u][tt] = MFMA_BF16(pf[i][u][1], vf1, O[i][u][tt]);
                }
        }
    }

    // ---- epilogue: Ao[n][h*128 + vc] = O1/l1 - lam*O2/l2 ----
    #pragma unroll
    for (int u = 0; u < 2; ++u) {
        float inv0[4], inv1[4];
        #pragma unroll
        for (int r = 0; r < 4; ++r) {
            inv0[r] = 1.0f / sm[0][u][r];
            inv1[r] = 1.0f / sm[1][u][r];
        }
        const int orow = qt * 64 + w * 32 + u * 16;
        #pragma unroll
        for (int tt = 0; tt < 8; ++tt)
            #pragma unroll
            for (int r = 0; r < 4; ++r) {
                float val = O[0][u][tt][r] * inv0[r] - lam * O[1][u][tt][r] * inv1[r];
                Ao[(size_t)(orow + q4 * 4 + r) * 2048 + h * 128 + tt * 16 + m16] = (bf16_t)val;
            }
    }
}

// ---------------------------------------------------------------------------
extern "C" void kernel_launch(void* const* d_in, const int* in_sizes, int n_in,
                              void* d_out, int out_size, void* d_ws, size_t ws_size,
                              hipStream_t stream) {
    const float* x     = (const float*)d_in[0];
    const float* Wqkv  = (const float*)d_in[1];
    const float* Wproj = (const float*)d_in[2];
    const float* lq1   = (const float*)d_in[3];
    const float* lq2   = (const float*)d_in[4];
    const float* lk1   = (const float*)d_in[5];
    const float* lk2   = (const float*)d_in[6];
    float* out = (float*)d_out;

    char* ws = (char*)d_ws;
    bf16_t* xb     = (bf16_t*)(ws);               //  4,194,304 B
    bf16_t* Ao     = (bf16_t*)(ws);               //  aliases xb/Wqkvb (dead post-QKV)
    bf16_t* Wqkvb  = (bf16_t*)(ws + 4194304);     // 12,582,912 B
    bf16_t* Wprojb = (bf16_t*)(ws + 16777216);    //  4,194,304 B
    bf16_t* Qb     = (bf16_t*)(ws + 20971520);    //  8,388,608 B
    bf16_t* Kb     = (bf16_t*)(ws + 29360128);    //  8,388,608 B
    bf16_t* Vt     = (bf16_t*)(ws + 37748736);    //  8,388,608 B
    float*  lamp   = (float*)(ws + 46137344);     //  4 B (total ~46.1 MB)

    lam_kernel<<<1, 64, 0, stream>>>(lq1, lq2, lk1, lk2, lamp);
    cast_bf16<<<1024, 256, 0, stream>>>(x, xb, 2048 * 1024 / 8);
    cast_bf16<<<3072, 256, 0, stream>>>(Wqkv, Wqkvb, 6144 * 1024 / 8);
    cast_bf16<<<1024, 256, 0, stream>>>(Wproj, Wprojb, 1024 * 2048 / 8);
    gemm_bt<128, 128, true, float><<<dim3(48, 16), 256, 0, stream>>>(
        xb, Wqkvb, (float*)nullptr, Qb, Kb, Vt, 2048, 6144, 1024);
    rotary_inplace<<<(2048 * 16 * 64) / 256, 256, 0, stream>>>(Qb, Kb);
    flash_diff<<<dim3(32, 16), 128, 0, stream>>>(Qb, Kb, Vt, lamp, Ao);
    gemm_bt<128, 64, false, float><<<dim3(16, 16), 256, 0, stream>>>(
        Ao, Wprojb, out, (bf16_t*)nullptr, (bf16_t*)nullptr, (bf16_t*)nullptr,
        2048, 1024, 2048);
}

// Round 11
// 303.246 us; speedup vs baseline: 1.4321x; 1.4321x over previous
//
#include <hip/hip_runtime.h>

using bf16_t = __bf16;
typedef __bf16 bf16x8 __attribute__((ext_vector_type(8)));
typedef float floatx4 __attribute__((ext_vector_type(4)));

#define MFMA_BF16(a, b, c) __builtin_amdgcn_mfma_f32_16x16x32_bf16((a), (b), (c), 0, 0, 0)

__device__ __forceinline__ void async_ld16(bf16_t* lds_dst, const bf16_t* g_src) {
    __builtin_amdgcn_global_load_lds(
        (const __attribute__((address_space(1))) void*)g_src,
        (__attribute__((address_space(3))) void*)lds_dst, 16, 0, 0);
}

// ---------------------------------------------------------------------------
// fp32 -> bf16 cast, 8 elements/thread
// ---------------------------------------------------------------------------
__global__ __launch_bounds__(256) void cast_bf16(const float* __restrict__ src,
                                                 bf16_t* __restrict__ dst, int n8) {
    int i = blockIdx.x * 256 + threadIdx.x;
    if (i < n8) {
        const floatx4 a = *(const floatx4*)(src + (size_t)i * 8);
        const floatx4 b = *(const floatx4*)(src + (size_t)i * 8 + 4);
        bf16x8 r;
        r[0] = (bf16_t)a[0]; r[1] = (bf16_t)a[1]; r[2] = (bf16_t)a[2]; r[3] = (bf16_t)a[3];
        r[4] = (bf16_t)b[0]; r[5] = (bf16_t)b[1]; r[6] = (bf16_t)b[2]; r[7] = (bf16_t)b[3];
        *(bf16x8*)(dst + (size_t)i * 8) = r;
    }
}

// ---------------------------------------------------------------------------
// lam = exp(sum(lq1*lk1)) - exp(sum(lq2*lk2)) + 0.2   (DEPTH=0)
// ---------------------------------------------------------------------------
__global__ void lam_kernel(const float* lq1, const float* lq2,
                           const float* lk1, const float* lk2, float* lamp) {
    int l = threadIdx.x;
    float p1 = lq1[l] * lk1[l];
    float p2 = lq2[l] * lk2[l];
    #pragma unroll
    for (int d = 1; d < 64; d <<= 1) {
        p1 += __shfl_xor(p1, d);
        p2 += __shfl_xor(p2, d);
    }
    if (l == 0) *lamp = expf(p1) - expf(p2) + 0.2f;
}

// ---------------------------------------------------------------------------
// GEMM (bf16): C[m][n] = sum_k A[m][k]*B[n][k]. BK=32, global_load_lds
// width-16 staging into [row][32] LDS, 16x16x32 MFMA, 2x2 waves.
// QKV_EPI routes into Qb/Kb ([inst][h][n][64], unrotated) and Vt ([h*128+vc][n]).
// ---------------------------------------------------------------------------
template <int BM, int BN, bool QKV_EPI, typename TC>
__global__ __launch_bounds__(256) void gemm_bt(const bf16_t* __restrict__ A,
                                               const bf16_t* __restrict__ B,
                                               TC* __restrict__ C,
                                               bf16_t* __restrict__ Qb,
                                               bf16_t* __restrict__ Kb,
                                               bf16_t* __restrict__ Vt,
                                               int M, int N, int K) {
    constexpr int BK = 32;
    __shared__ __align__(16) bf16_t As[BM * BK];
    __shared__ __align__(16) bf16_t Bs[BN * BK];
    const int t = threadIdx.x;
    const int lane = t & 63, wave = t >> 6;
    const int q4 = lane >> 4, m16 = lane & 15;
    const int mblk = blockIdx.y * BM, nblk = blockIdx.x * BN;
    const int wr = wave >> 1, wc = wave & 1;
    constexpr int WM = BM / 2, WN = BN / 2;
    constexpr int NI = WM / 16, NJ = WN / 16;
    constexpr int AR = BM * BK / 2048;
    constexpr int BR = BN * BK / 2048;

    floatx4 acc[NI][NJ] = {};

    for (int k0 = 0; k0 < K; k0 += BK) {
        __syncthreads();
        #pragma unroll
        for (int rr = 0; rr < AR; ++rr) {
            int f = rr * 256 + t;
            async_ld16(&As[f * 8], &A[(size_t)(mblk + (f >> 2)) * K + k0 + (f & 3) * 8]);
        }
        #pragma unroll
        for (int rr = 0; rr < BR; ++rr) {
            int f = rr * 256 + t;
            async_ld16(&Bs[f * 8], &B[(size_t)(nblk + (f >> 2)) * K + k0 + (f & 3) * 8]);
        }
        __syncthreads();

        bf16x8 a[NI], b[NJ];
        #pragma unroll
        for (int i = 0; i < NI; ++i)
            a[i] = *(const bf16x8*)&As[(wr * WM + i * 16 + m16) * 32 + q4 * 8];
        #pragma unroll
        for (int j = 0; j < NJ; ++j)
            b[j] = *(const bf16x8*)&Bs[(wc * WN + j * 16 + m16) * 32 + q4 * 8];
        #pragma unroll
        for (int i = 0; i < NI; ++i)
            #pragma unroll
            for (int j = 0; j < NJ; ++j)
                acc[i][j] = MFMA_BF16(a[i], b[j], acc[i][j]);
    }

    #pragma unroll
    for (int i = 0; i < NI; ++i)
        #pragma unroll
        for (int j = 0; j < NJ; ++j) {
            int n = nblk + wc * WN + j * 16 + m16;
            #pragma unroll
            for (int r = 0; r < 4; ++r) {
                int m = mblk + wr * WM + i * 16 + q4 * 4 + r;
                if constexpr (QKV_EPI) {
                    bf16_t val = (bf16_t)acc[i][j][r];
                    int comp = n >> 10, h = (n >> 6) & 15, e = n & 63;
                    if (comp < 2)
                        Qb[(size_t)((comp * 16 + h) * 2048 + m) * 64 + e] = val;
                    else if (comp < 4)
                        Kb[(size_t)(((comp - 2) * 16 + h) * 2048 + m) * 64 + e] = val;
                    else
                        Vt[(size_t)(h * 128 + (comp - 4) * 64 + e) * 2048 + m] = val;
                } else {
                    C[(size_t)m * N + n] = (TC)acc[i][j][r];
                }
            }
        }
}

// ---------------------------------------------------------------------------
// In-place rotary on Qb/Kb [inst][h][n][64]
// ---------------------------------------------------------------------------
__global__ __launch_bounds__(256) void rotary_inplace(bf16_t* __restrict__ Qb,
                                                      bf16_t* __restrict__ Kb) {
    int t = blockIdx.x * 256 + threadIdx.x;
    int e = t & 63, h = (t >> 6) & 15, n = t >> 10;
    float invf = exp2f(-(float)e * (13.287712379549449f / 64.0f));
    float ang = (float)n * invf;
    float s, c;
    sincosf(ang, &s, &c);
    int off = (h * 2048 + n) * 64 + e;
    float q1 = (float)Qb[off], q2 = (float)Qb[off + 2097152];
    Qb[off]           = (bf16_t)(q1 * c - q2 * s);
    Qb[off + 2097152] = (bf16_t)(q2 * c + q1 * s);
    float k1 = (float)Kb[off], k2 = (float)Kb[off + 2097152];
    Kb[off]           = (bf16_t)(k1 * c - k2 * s);
    Kb[off + 2097152] = (bf16_t)(k2 * c + k1 * s);
}

// ---------------------------------------------------------------------------
// Differential flash attention, v5.
//  - r8 MFMA orientation (A=Q, B=K) — the fastest verified structure.
//  - Async global_load_lds staging straight into UNPADDED fragment-order LDS:
//    lane order == fragment order (wave-uniform base + lane*16B contract),
//    so fragment reads are contiguous conflict-free b128 and the register
//    staging round-trip disappears.
//  - qt split 32->64 blocks (32 q-rows, 2 waves x 16 rows, 40KB LDS):
//    1024 blocks = 4 blocks/CU so barrier drains overlap across blocks.
//  - Fixed-max softmax; ones-MFMA row sums; Pf wave-private region.
// grid (64 qtiles x 16 heads), 128 thr, 64 keys/chunk, 2 barriers/chunk.
// ---------------------------------------------------------------------------
__global__ __launch_bounds__(128, 2) void flash_diff(const bf16_t* __restrict__ Qb,
                                                     const bf16_t* __restrict__ Kb,
                                                     const bf16_t* __restrict__ Vt,
                                                     const float* __restrict__ lamp,
                                                     bf16_t* __restrict__ Ao) {
    constexpr int N = 2048, BN = 64;
    // Kf: [i2][s4][half2] spans of 512 elems, each span = [qq4][mm16][8]
    // Vf: [tt8][half2] spans of 512 elems, each span = [qq4][mm16][8]
    // Pf: [w2][i2][half2][quad4][m16 16][8]
    __shared__ __align__(16) bf16_t Kf[16 * 512];   // 16 KB
    __shared__ __align__(16) bf16_t Vf[16 * 512];   // 16 KB
    __shared__ __align__(16) bf16_t Pf[2 * 2 * 1024];  // 8 KB
    const int t = threadIdx.x, lane = t & 63, w = t >> 6;  // w in {0,1}
    const int q4 = lane >> 4, m16 = lane & 15;
    const int h = blockIdx.y, qt = blockIdx.x;
    const float lam = *lamp;
    const float cexp = 0.125f * 1.4426950408889634f;  // scale * log2(e)
    const int mm = lane & 15, qq = lane >> 4;

    // Q fragments (A-operand: m=m16 -> qrow, k=q4*8+j -> e)
    bf16x8 qf[2][2];
    const int qrow = qt * 32 + w * 16 + m16;
    #pragma unroll
    for (int i = 0; i < 2; ++i)
        #pragma unroll
        for (int kc = 0; kc < 2; ++kc)
            qf[i][kc] = *(const bf16x8*)&Qb[(size_t)((i * 16 + h) * 2048 + qrow) * 64 + kc * 32 + q4 * 8];

    bf16x8 ones;
    #pragma unroll
    for (int j = 0; j < 8; ++j) ones[j] = (bf16_t)1.0f;

    floatx4 O[2][8] = {};
    floatx4 sm[2] = {};

    for (int k0 = 0; k0 < N; k0 += BN) {
        __syncthreads();  // prev chunk's Kf/Vf reads complete
        // ---- async staging, fragment-order (16 instrs/wave, 32/block) ----
        #pragma unroll
        for (int rr = 0; rr < 16; ++rr) {
            int idx = w * 16 + rr;
            if (idx < 16) {
                // Kf span idx = ((i*4+s)*2+half): element (key=16s+mm, e=32half+8qq+j)
                int i = idx >> 3, s = (idx >> 1) & 3, half = idx & 1;
                async_ld16(&Kf[idx * 512],
                           &Kb[(size_t)((i * 16 + h) * 2048 + k0 + 16 * s + mm) * 64 + half * 32 + qq * 8]);
            } else {
                // Vf span v = (tt*2+half): element (vc=16tt+mm, key=32half+8qq+j)
                int v = idx - 16, tt = v >> 1, half = v & 1;
                async_ld16(&Vf[v * 512],
                           &Vt[(size_t)(h * 128 + tt * 16 + mm) * 2048 + k0 + half * 32 + qq * 8]);
            }
        }
        __syncthreads();  // drains vmcnt -> staged tiles visible

        // ---- S = Q K^T, p = exp2(S*cexp), P-store in A-frag order ----
        #pragma unroll
        for (int i = 0; i < 2; ++i) {
            #pragma unroll
            for (int s = 0; s < 4; ++s) {
                floatx4 sacc = {};
                const bf16x8 kf0 = *(const bf16x8*)&Kf[((i * 4 + s) * 2 + 0) * 512 + (q4 * 16 + m16) * 8];
                const bf16x8 kf1 = *(const bf16x8*)&Kf[((i * 4 + s) * 2 + 1) * 512 + (q4 * 16 + m16) * 8];
                sacc = MFMA_BF16(qf[i][0], kf0, sacc);  // D[qrow][key]
                sacc = MFMA_BF16(qf[i][1], kf1, sacc);
                // element (qrow=4q4+r, key=16s+m16) -> Pf[w][i] at
                // half=s>>1, quad=(2s+(m16>>3))&3, row=qrow, j=m16&7
                const int half = s >> 1, quad = (2 * s + (m16 >> 3)) & 3, jj = m16 & 7;
                bf16_t* pb = &Pf[((w * 2 + i) * 2 + half) * 512 + quad * 128 + jj];
                #pragma unroll
                for (int r = 0; r < 4; ++r)
                    pb[(q4 * 4 + r) * 8] = (bf16_t)exp2f(sacc[r] * cexp);
            }
        }
        __syncthreads();  // P visible; K/V reads done before next staging

        // ---- P reads (contiguous A-frag), row sums, PV ----
        bf16x8 pf[2][2];
        #pragma unroll
        for (int i = 0; i < 2; ++i) {
            pf[i][0] = *(const bf16x8*)&Pf[((w * 2 + i) * 2 + 0) * 512 + (q4 * 16 + m16) * 8];
            pf[i][1] = *(const bf16x8*)&Pf[((w * 2 + i) * 2 + 1) * 512 + (q4 * 16 + m16) * 8];
            sm[i] = MFMA_BF16(pf[i][0], ones, sm[i]);
            sm[i] = MFMA_BF16(pf[i][1], ones, sm[i]);
        }
        #pragma unroll
        for (int tt = 0; tt < 8; ++tt) {
            const bf16x8 vf0 = *(const bf16x8*)&Vf[(tt * 2 + 0) * 512 + (q4 * 16 + m16) * 8];
            const bf16x8 vf1 = *(const bf16x8*)&Vf[(tt * 2 + 1) * 512 + (q4 * 16 + m16) * 8];
            #pragma unroll
            for (int i = 0; i < 2; ++i) {
                O[i][tt] = MFMA_BF16(pf[i][0], vf0, O[i][tt]);
                O[i][tt] = MFMA_BF16(pf[i][1], vf1, O[i][tt]);
            }
        }
    }

    // ---- epilogue: Ao[n][h*128 + vc] = O1/l1 - lam*O2/l2 ----
    float inv0[4], inv1[4];
    #pragma unroll
    for (int r = 0; r < 4; ++r) {
        inv0[r] = 1.0f / sm[0][r];
        inv1[r] = 1.0f / sm[1][r];
    }
    const int orow = qt * 32 + w * 16;
    #pragma unroll
    for (int tt = 0; tt < 8; ++tt)
        #pragma unroll
        for (int r = 0; r < 4; ++r) {
            float val = O[0][tt][r] * inv0[r] - lam * O[1][tt][r] * inv1[r];
            Ao[(size_t)(orow + q4 * 4 + r) * 2048 + h * 128 + tt * 16 + m16] = (bf16_t)val;
        }
}

// ---------------------------------------------------------------------------
extern "C" void kernel_launch(void* const* d_in, const int* in_sizes, int n_in,
                              void* d_out, int out_size, void* d_ws, size_t ws_size,
                              hipStream_t stream) {
    const float* x     = (const float*)d_in[0];
    const float* Wqkv  = (const float*)d_in[1];
    const float* Wproj = (const float*)d_in[2];
    const float* lq1   = (const float*)d_in[3];
    const float* lq2   = (const float*)d_in[4];
    const float* lk1   = (const float*)d_in[5];
    const float* lk2   = (const float*)d_in[6];
    float* out = (float*)d_out;

    char* ws = (char*)d_ws;
    bf16_t* xb     = (bf16_t*)(ws);               //  4,194,304 B
    bf16_t* Ao     = (bf16_t*)(ws);               //  aliases xb/Wqkvb (dead post-QKV)
    bf16_t* Wqkvb  = (bf16_t*)(ws + 4194304);     // 12,582,912 B
    bf16_t* Wprojb = (bf16_t*)(ws + 16777216);    //  4,194,304 B
    bf16_t* Qb     = (bf16_t*)(ws + 20971520);    //  8,388,608 B
    bf16_t* Kb     = (bf16_t*)(ws + 29360128);    //  8,388,608 B
    bf16_t* Vt     = (bf16_t*)(ws + 37748736);    //  8,388,608 B
    float*  lamp   = (float*)(ws + 46137344);     //  4 B (total ~46.1 MB)

    lam_kernel<<<1, 64, 0, stream>>>(lq1, lq2, lk1, lk2, lamp);
    cast_bf16<<<1024, 256, 0, stream>>>(x, xb, 2048 * 1024 / 8);
    cast_bf16<<<3072, 256, 0, stream>>>(Wqkv, Wqkvb, 6144 * 1024 / 8);
    cast_bf16<<<1024, 256, 0, stream>>>(Wproj, Wprojb, 1024 * 2048 / 8);
    gemm_bt<128, 128, true, float><<<dim3(48, 16), 256, 0, stream>>>(
        xb, Wqkvb, (float*)nullptr, Qb, Kb, Vt, 2048, 6144, 1024);
    rotary_inplace<<<(2048 * 16 * 64) / 256, 256, 0, stream>>>(Qb, Kb);
    flash_diff<<<dim3(64, 16), 128, 0, stream>>>(Qb, Kb, Vt, lamp, Ao);
    gemm_bt<128, 64, false, float><<<dim3(16, 16), 256, 0, stream>>>(
        Ao, Wprojb, out, (bf16_t*)nullptr, (bf16_t*)nullptr, (bf16_t*)nullptr,
        2048, 1024, 2048);
}

// Round 12
// 280.525 us; speedup vs baseline: 1.5481x; 1.0810x over previous
//
#include <hip/hip_runtime.h>

using bf16_t = __bf16;
typedef __bf16 bf16x8 __attribute__((ext_vector_type(8)));
typedef float floatx4 __attribute__((ext_vector_type(4)));

#define MFMA_BF16(a, b, c) __builtin_amdgcn_mfma_f32_16x16x32_bf16((a), (b), (c), 0, 0, 0)

__device__ __forceinline__ void async_ld16(bf16_t* lds_dst, const bf16_t* g_src) {
    __builtin_amdgcn_global_load_lds(
        (const __attribute__((address_space(1))) void*)g_src,
        (__attribute__((address_space(3))) void*)lds_dst, 16, 0, 0);
}

// ---------------------------------------------------------------------------
// fp32 -> bf16 cast, 8 elements/thread
// ---------------------------------------------------------------------------
__global__ __launch_bounds__(256) void cast_bf16(const float* __restrict__ src,
                                                 bf16_t* __restrict__ dst, int n8) {
    int i = blockIdx.x * 256 + threadIdx.x;
    if (i < n8) {
        const floatx4 a = *(const floatx4*)(src + (size_t)i * 8);
        const floatx4 b = *(const floatx4*)(src + (size_t)i * 8 + 4);
        bf16x8 r;
        r[0] = (bf16_t)a[0]; r[1] = (bf16_t)a[1]; r[2] = (bf16_t)a[2]; r[3] = (bf16_t)a[3];
        r[4] = (bf16_t)b[0]; r[5] = (bf16_t)b[1]; r[6] = (bf16_t)b[2]; r[7] = (bf16_t)b[3];
        *(bf16x8*)(dst + (size_t)i * 8) = r;
    }
}

// ---------------------------------------------------------------------------
// lam = exp(sum(lq1*lk1)) - exp(sum(lq2*lk2)) + 0.2   (DEPTH=0)
// ---------------------------------------------------------------------------
__global__ void lam_kernel(const float* lq1, const float* lq2,
                           const float* lk1, const float* lk2, float* lamp) {
    int l = threadIdx.x;
    float p1 = lq1[l] * lk1[l];
    float p2 = lq2[l] * lk2[l];
    #pragma unroll
    for (int d = 1; d < 64; d <<= 1) {
        p1 += __shfl_xor(p1, d);
        p2 += __shfl_xor(p2, d);
    }
    if (l == 0) *lamp = expf(p1) - expf(p2) + 0.2f;
}

// ---------------------------------------------------------------------------
// GEMM (bf16): C[m][n] = sum_k A[m][k]*B[n][k]. BK=32, global_load_lds
// width-16 staging into [row][32] LDS, 16x16x32 MFMA, 2x2 waves.
// QKV_EPI routes into Qb/Kb ([inst][h][n][64], unrotated) and Vt ([h*128+vc][n]).
// ---------------------------------------------------------------------------
template <int BM, int BN, bool QKV_EPI, typename TC>
__global__ __launch_bounds__(256) void gemm_bt(const bf16_t* __restrict__ A,
                                               const bf16_t* __restrict__ B,
                                               TC* __restrict__ C,
                                               bf16_t* __restrict__ Qb,
                                               bf16_t* __restrict__ Kb,
                                               bf16_t* __restrict__ Vt,
                                               int M, int N, int K) {
    constexpr int BK = 32;
    __shared__ __align__(16) bf16_t As[BM * BK];
    __shared__ __align__(16) bf16_t Bs[BN * BK];
    const int t = threadIdx.x;
    const int lane = t & 63, wave = t >> 6;
    const int q4 = lane >> 4, m16 = lane & 15;
    const int mblk = blockIdx.y * BM, nblk = blockIdx.x * BN;
    const int wr = wave >> 1, wc = wave & 1;
    constexpr int WM = BM / 2, WN = BN / 2;
    constexpr int NI = WM / 16, NJ = WN / 16;
    constexpr int AR = BM * BK / 2048;
    constexpr int BR = BN * BK / 2048;

    floatx4 acc[NI][NJ] = {};

    for (int k0 = 0; k0 < K; k0 += BK) {
        __syncthreads();
        #pragma unroll
        for (int rr = 0; rr < AR; ++rr) {
            int f = rr * 256 + t;
            async_ld16(&As[f * 8], &A[(size_t)(mblk + (f >> 2)) * K + k0 + (f & 3) * 8]);
        }
        #pragma unroll
        for (int rr = 0; rr < BR; ++rr) {
            int f = rr * 256 + t;
            async_ld16(&Bs[f * 8], &B[(size_t)(nblk + (f >> 2)) * K + k0 + (f & 3) * 8]);
        }
        __syncthreads();

        bf16x8 a[NI], b[NJ];
        #pragma unroll
        for (int i = 0; i < NI; ++i)
            a[i] = *(const bf16x8*)&As[(wr * WM + i * 16 + m16) * 32 + q4 * 8];
        #pragma unroll
        for (int j = 0; j < NJ; ++j)
            b[j] = *(const bf16x8*)&Bs[(wc * WN + j * 16 + m16) * 32 + q4 * 8];
        #pragma unroll
        for (int i = 0; i < NI; ++i)
            #pragma unroll
            for (int j = 0; j < NJ; ++j)
                acc[i][j] = MFMA_BF16(a[i], b[j], acc[i][j]);
    }

    #pragma unroll
    for (int i = 0; i < NI; ++i)
        #pragma unroll
        for (int j = 0; j < NJ; ++j) {
            int n = nblk + wc * WN + j * 16 + m16;
            #pragma unroll
            for (int r = 0; r < 4; ++r) {
                int m = mblk + wr * WM + i * 16 + q4 * 4 + r;
                if constexpr (QKV_EPI) {
                    bf16_t val = (bf16_t)acc[i][j][r];
                    int comp = n >> 10, h = (n >> 6) & 15, e = n & 63;
                    if (comp < 2)
                        Qb[(size_t)((comp * 16 + h) * 2048 + m) * 64 + e] = val;
                    else if (comp < 4)
                        Kb[(size_t)(((comp - 2) * 16 + h) * 2048 + m) * 64 + e] = val;
                    else
                        Vt[(size_t)(h * 128 + (comp - 4) * 64 + e) * 2048 + m] = val;
                } else {
                    C[(size_t)m * N + n] = (TC)acc[i][j][r];
                }
            }
        }
}

// ---------------------------------------------------------------------------
// In-place rotary on Qb/Kb [inst][h][n][64]
// ---------------------------------------------------------------------------
__global__ __launch_bounds__(256) void rotary_inplace(bf16_t* __restrict__ Qb,
                                                      bf16_t* __restrict__ Kb) {
    int t = blockIdx.x * 256 + threadIdx.x;
    int e = t & 63, h = (t >> 6) & 15, n = t >> 10;
    float invf = exp2f(-(float)e * (13.287712379549449f / 64.0f));
    float ang = (float)n * invf;
    float s, c;
    sincosf(ang, &s, &c);
    int off = (h * 2048 + n) * 64 + e;
    float q1 = (float)Qb[off], q2 = (float)Qb[off + 2097152];
    Qb[off]           = (bf16_t)(q1 * c - q2 * s);
    Qb[off + 2097152] = (bf16_t)(q2 * c + q1 * s);
    float k1 = (float)Kb[off], k2 = (float)Kb[off + 2097152];
    Kb[off]           = (bf16_t)(k1 * c - k2 * s);
    Kb[off + 2097152] = (bf16_t)(k2 * c + k1 * s);
}

// ---------------------------------------------------------------------------
// Differential flash attention, v6 = r8 geometry + v5 async staging.
//  - 4 waves/block (256 thr), each wave 16 q-rows; 32 qtiles x 16 heads =
//    512 blocks, 48 KB LDS -> 3 blocks/CU = 12 waves/CU (barrier overlap),
//    and staging duplication halves vs v5 (block tile shared by 4 waves).
//  - Async global_load_lds staging into unpadded fragment-order LDS
//    (lane order == fragment order; conflict-free contiguous b128 reads).
//  - Fixed-max softmax; ones-MFMA row sums; Pf wave-private region.
// ---------------------------------------------------------------------------
__global__ __launch_bounds__(256, 2) void flash_diff(const bf16_t* __restrict__ Qb,
                                                     const bf16_t* __restrict__ Kb,
                                                     const bf16_t* __restrict__ Vt,
                                                     const float* __restrict__ lamp,
                                                     bf16_t* __restrict__ Ao) {
    constexpr int N = 2048, BN = 64;
    // Kf: [i2][s4][half2] spans of 512; Vf: [tt8][half2] spans of 512;
    // span = [qq4][mm16][8] (lane-ordered). Pf: [w4][i2][half2][quad4][row16][8]
    __shared__ __align__(16) bf16_t Kf[16 * 512];      // 16 KB
    __shared__ __align__(16) bf16_t Vf[16 * 512];      // 16 KB
    __shared__ __align__(16) bf16_t Pf[4 * 2 * 1024];  // 16 KB
    const int t = threadIdx.x, lane = t & 63, w = t >> 6;  // w in {0..3}
    const int q4 = lane >> 4, m16 = lane & 15;
    const int h = blockIdx.y, qt = blockIdx.x;
    const float lam = *lamp;
    const float cexp = 0.125f * 1.4426950408889634f;  // scale * log2(e)
    const int mm = lane & 15, qq = lane >> 4;

    // Q fragments (A-operand: m=m16 -> qrow, k=q4*8+j -> e)
    bf16x8 qf[2][2];
    const int qrow = qt * 64 + w * 16 + m16;
    #pragma unroll
    for (int i = 0; i < 2; ++i)
        #pragma unroll
        for (int kc = 0; kc < 2; ++kc)
            qf[i][kc] = *(const bf16x8*)&Qb[(size_t)((i * 16 + h) * 2048 + qrow) * 64 + kc * 32 + q4 * 8];

    bf16x8 ones;
    #pragma unroll
    for (int j = 0; j < 8; ++j) ones[j] = (bf16_t)1.0f;

    floatx4 O[2][8] = {};
    floatx4 sm[2] = {};

    for (int k0 = 0; k0 < N; k0 += BN) {
        __syncthreads();  // prev chunk's Kf/Vf reads complete
        // ---- async staging, fragment-order: 32 spans, 8 per wave ----
        #pragma unroll
        for (int rr = 0; rr < 8; ++rr) {
            int idx = w * 8 + rr;
            if (idx < 16) {
                // Kf span ((i*4+s)*2+half): element (key=16s+mm, e=32half+8qq+j)
                int i = idx >> 3, s = (idx >> 1) & 3, half = idx & 1;
                async_ld16(&Kf[idx * 512],
                           &Kb[(size_t)((i * 16 + h) * 2048 + k0 + 16 * s + mm) * 64 + half * 32 + qq * 8]);
            } else {
                // Vf span (tt*2+half): element (vc=16tt+mm, key=32half+8qq+j)
                int v = idx - 16, tt = v >> 1, half = v & 1;
                async_ld16(&Vf[v * 512],
                           &Vt[(size_t)(h * 128 + tt * 16 + mm) * 2048 + k0 + half * 32 + qq * 8]);
            }
        }
        __syncthreads();  // drains vmcnt -> staged tiles visible

        // ---- S = Q K^T, p = exp2(S*cexp), P-store in A-frag order ----
        #pragma unroll
        for (int i = 0; i < 2; ++i) {
            #pragma unroll
            for (int s = 0; s < 4; ++s) {
                floatx4 sacc = {};
                const bf16x8 kf0 = *(const bf16x8*)&Kf[((i * 4 + s) * 2 + 0) * 512 + (q4 * 16 + m16) * 8];
                const bf16x8 kf1 = *(const bf16x8*)&Kf[((i * 4 + s) * 2 + 1) * 512 + (q4 * 16 + m16) * 8];
                sacc = MFMA_BF16(qf[i][0], kf0, sacc);  // D[qrow][key]
                sacc = MFMA_BF16(qf[i][1], kf1, sacc);
                // element (qrow=4q4+r, key=16s+m16) -> half=s>>1,
                // quad=(2s+(m16>>3))&3, row=qrow, j=m16&7  (verified r11)
                const int half = s >> 1, quad = (2 * s + (m16 >> 3)) & 3, jj = m16 & 7;
                bf16_t* pb = &Pf[((w * 2 + i) * 2 + half) * 512 + quad * 128 + jj];
                #pragma unroll
                for (int r = 0; r < 4; ++r)
                    pb[(q4 * 4 + r) * 8] = (bf16_t)exp2f(sacc[r] * cexp);
            }
        }
        __syncthreads();  // P visible; K/V reads done before next staging

        // ---- P reads (contiguous A-frag), row sums, PV ----
        bf16x8 pf[2][2];
        #pragma unroll
        for (int i = 0; i < 2; ++i) {
            pf[i][0] = *(const bf16x8*)&Pf[((w * 2 + i) * 2 + 0) * 512 + (q4 * 16 + m16) * 8];
            pf[i][1] = *(const bf16x8*)&Pf[((w * 2 + i) * 2 + 1) * 512 + (q4 * 16 + m16) * 8];
            sm[i] = MFMA_BF16(pf[i][0], ones, sm[i]);
            sm[i] = MFMA_BF16(pf[i][1], ones, sm[i]);
        }
        #pragma unroll
        for (int tt = 0; tt < 8; ++tt) {
            const bf16x8 vf0 = *(const bf16x8*)&Vf[(tt * 2 + 0) * 512 + (q4 * 16 + m16) * 8];
            const bf16x8 vf1 = *(const bf16x8*)&Vf[(tt * 2 + 1) * 512 + (q4 * 16 + m16) * 8];
            #pragma unroll
            for (int i = 0; i < 2; ++i) {
                O[i][tt] = MFMA_BF16(pf[i][0], vf0, O[i][tt]);
                O[i][tt] = MFMA_BF16(pf[i][1], vf1, O[i][tt]);
            }
        }
    }

    // ---- epilogue: Ao[n][h*128 + vc] = O1/l1 - lam*O2/l2 ----
    float inv0[4], inv1[4];
    #pragma unroll
    for (int r = 0; r < 4; ++r) {
        inv0[r] = 1.0f / sm[0][r];
        inv1[r] = 1.0f / sm[1][r];
    }
    const int orow = qt * 64 + w * 16;
    #pragma unroll
    for (int tt = 0; tt < 8; ++tt)
        #pragma unroll
        for (int r = 0; r < 4; ++r) {
            float val = O[0][tt][r] * inv0[r] - lam * O[1][tt][r] * inv1[r];
            Ao[(size_t)(orow + q4 * 4 + r) * 2048 + h * 128 + tt * 16 + m16] = (bf16_t)val;
        }
}

// ---------------------------------------------------------------------------
extern "C" void kernel_launch(void* const* d_in, const int* in_sizes, int n_in,
                              void* d_out, int out_size, void* d_ws, size_t ws_size,
                              hipStream_t stream) {
    const float* x     = (const float*)d_in[0];
    const float* Wqkv  = (const float*)d_in[1];
    const float* Wproj = (const float*)d_in[2];
    const float* lq1   = (const float*)d_in[3];
    const float* lq2   = (const float*)d_in[4];
    const float* lk1   = (const float*)d_in[5];
    const float* lk2   = (const float*)d_in[6];
    float* out = (float*)d_out;

    char* ws = (char*)d_ws;
    bf16_t* xb     = (bf16_t*)(ws);               //  4,194,304 B
    bf16_t* Ao     = (bf16_t*)(ws);               //  aliases xb/Wqkvb (dead post-QKV)
    bf16_t* Wqkvb  = (bf16_t*)(ws + 4194304);     // 12,582,912 B
    bf16_t* Wprojb = (bf16_t*)(ws + 16777216);    //  4,194,304 B
    bf16_t* Qb     = (bf16_t*)(ws + 20971520);    //  8,388,608 B
    bf16_t* Kb     = (bf16_t*)(ws + 29360128);    //  8,388,608 B
    bf16_t* Vt     = (bf16_t*)(ws + 37748736);    //  8,388,608 B
    float*  lamp   = (float*)(ws + 46137344);     //  4 B (total ~46.1 MB)

    lam_kernel<<<1, 64, 0, stream>>>(lq1, lq2, lk1, lk2, lamp);
    cast_bf16<<<1024, 256, 0, stream>>>(x, xb, 2048 * 1024 / 8);
    cast_bf16<<<3072, 256, 0, stream>>>(Wqkv, Wqkvb, 6144 * 1024 / 8);
    cast_bf16<<<1024, 256, 0, stream>>>(Wproj, Wprojb, 1024 * 2048 / 8);
    gemm_bt<128, 128, true, float><<<dim3(48, 16), 256, 0, stream>>>(
        xb, Wqkvb, (float*)nullptr, Qb, Kb, Vt, 2048, 6144, 1024);
    rotary_inplace<<<(2048 * 16 * 64) / 256, 256, 0, stream>>>(Qb, Kb);
    flash_diff<<<dim3(32, 16), 256, 0, stream>>>(Qb, Kb, Vt, lamp, Ao);
    gemm_bt<128, 64, false, float><<<dim3(16, 16), 256, 0, stream>>>(
        Ao, Wprojb, out, (bf16_t*)nullptr, (bf16_t*)nullptr, (bf16_t*)nullptr,
        2048, 1024, 2048);
}